// Round 9
// baseline (201.274 us; speedup 1.0000x reference)
//
#include <hip/hip_runtime.h>

// REConv forward via dst-CSR gather. Zero scattered global atomics, and the
// R8 bottleneck (8x region-replicated edge scans in hist/bucket) replaced by
// an exact 3-phase partition:
//   1. countA:    512 slice-blocks count edges per dst-region & src-region (one scan)
//   2. scanC:     region-major exclusive scan of counts -> per-(slice,region) bases
//   3. partition: one scan; scatter (src,dst) -> dstpart, src -> srcpart
//                 (8+8 LDS bump cursors; blocks own disjoint exact output ranges)
//   4. histIn:    per (chunk,region) LDS histogram of dst over region-local bins
//   5. reduceIn:  -> indeg;  scan1/2/3 -> offsets;  pboff -> per-(chunk,region,bin) starts
//   6. bucket2:   LDS-cursor scatter of region edges -> sorted_src (reads region once)
//   7. histOut/reduceOut on srcpart -> outdeg
//   8. transform: h16 = bf16((feat * outdeg^-1/2 * wtype[type]) @ W)  (h16 aliases dstpart)
//   9. gather:    one wave per dst node, 2 edges/wave-load, fused indeg^-1/2 + bias
// Regions are pow2 (16384 nodes, >>14): no division anywhere.
// F_IN = F_OUT = 64 hardcoded.

#define THREADS 256
#define SCAN_CHUNK 1024
#define PSLICE 512        // partition slices
#define NREG 8            // pow2 regions of 16384 nodes (region 7 empty for N=100k)
#define RSH 14
#define NBIN 16384        // bins per region; LDS hist = 64 KB
#define NCHUNK 32         // hist/bucket chunks per region

__device__ __forceinline__ unsigned f2bf(float f) {   // RTNE f32->bf16 bits
    unsigned x = __float_as_uint(f);
    return (x + 0x7fffu + ((x >> 16) & 1u)) >> 16;
}

// Per-slice counts of edges by dst-region (lo16) and src-region (hi16).
__global__ void countA_kernel(const int* __restrict__ src, const int* __restrict__ dst,
                              unsigned* __restrict__ countsD, unsigned* __restrict__ countsS,
                              int E, int chunk) {
    __shared__ unsigned lds[256 * 9];   // per-thread row (stride 9: bank-spread), packed d|s<<16
    __shared__ unsigned red[8][32];
    int t = threadIdx.x;
#pragma unroll
    for (int r = 0; r < 8; ++r) lds[t * 9 + r] = 0u;
    int beg = blockIdx.x * chunk, end = min(E, beg + chunk);
    for (int i = beg + t; i < end; i += THREADS) {
        int d = dst[i], s = src[i];
        lds[t * 9 + (d >> RSH)] += 1u;
        lds[t * 9 + (s >> RSH)] += 65536u;
    }
    __syncthreads();
    int r = t & 7, g = t >> 3;          // g in [0,32): rows g*8..g*8+7
    unsigned acc = 0;
#pragma unroll
    for (int k = 0; k < 8; ++k) acc += lds[(g * 8 + k) * 9 + r];
    red[r][g] = acc;
    __syncthreads();
    if (t < 8) {
        unsigned tot = 0;
#pragma unroll
        for (int k = 0; k < 32; ++k) tot += red[t][k];
        countsD[blockIdx.x * 8 + t] = tot & 0xffffu;
        countsS[blockIdx.x * 8 + t] = tot >> 16;
    }
}

// Exclusive scan of counts[s*8+r] in region-major order o=r*512+s -> base[o]; rbase[r]=region start.
__global__ void scanC_kernel(const unsigned* __restrict__ counts, unsigned* __restrict__ base,
                             unsigned* __restrict__ rbase, int E) {
    __shared__ unsigned sdata[1024];
    int t = threadIdx.x;
    unsigned v[4], sum = 0;
#pragma unroll
    for (int k = 0; k < 4; ++k) {
        int o = t * 4 + k;
        v[k] = counts[(o & 511) * 8 + (o >> 9)];
        sum += v[k];
    }
    sdata[t] = sum;
    __syncthreads();
    for (int off = 1; off < 1024; off <<= 1) {
        unsigned x = (t >= off) ? sdata[t - off] : 0u;
        __syncthreads();
        sdata[t] += x;
        __syncthreads();
    }
    unsigned run = sdata[t] - sum;
    if (((t * 4) & 511) == 0) rbase[(t * 4) >> 9] = run;
    if (t == 1023) rbase[8] = sdata[1023];
#pragma unroll
    for (int k = 0; k < 4; ++k) { base[t * 4 + k] = run; run += v[k]; }
}

// One scan: scatter (src,dst) into dst-region partition, src into src-region partition.
__global__ void partition_kernel(const int* __restrict__ src, const int* __restrict__ dst,
                                 const unsigned* __restrict__ dbase, const unsigned* __restrict__ sbase,
                                 int2* __restrict__ dstpart, int* __restrict__ srcpart,
                                 int E, int chunk) {
    __shared__ unsigned curD[8], curS[8];
    int t = threadIdx.x;
    if (t < 8) {
        curD[t] = dbase[t * PSLICE + blockIdx.x];
        curS[t] = sbase[t * PSLICE + blockIdx.x];
    }
    __syncthreads();
    int beg = blockIdx.x * chunk, end = min(E, beg + chunk);
    for (int i = beg + t; i < end; i += THREADS) {
        int s = src[i], d = dst[i];
        unsigned p = atomicAdd(&curD[d >> RSH], 1u);
        dstpart[p] = make_int2(s, d);
        unsigned q = atomicAdd(&curS[s >> RSH], 1u);
        srcpart[q] = s;
    }
}

// Unified region histogram: block (j,r) reads chunk j of region r's partitioned data.
// data element i's key = data[i*stride + offs]; bin = key & (NBIN-1).
__global__ void histP_kernel(const int* __restrict__ data, int stride, int offs,
                             const unsigned* __restrict__ rbase,
                             unsigned* __restrict__ partial, int N) {
    __shared__ unsigned hist[NBIN];
    int r = blockIdx.x & 7, j = blockIdx.x >> 3;
    if (r * NBIN >= N) return;           // region holds no real nodes: partial never read
    int t = threadIdx.x;
    for (int b = t; b < NBIN; b += THREADS) hist[b] = 0u;
    __syncthreads();
    unsigned s0 = rbase[r], s1 = rbase[r + 1];
    unsigned chunk = (s1 - s0 + NCHUNK - 1) >> 5;
    unsigned beg = s0 + j * chunk, end = min(s1, beg + chunk);
    for (unsigned i = beg + t; i < end; i += THREADS) {
        int d = data[(size_t)i * stride + offs];
        atomicAdd(&hist[d & (NBIN - 1)], 1u);
    }
    __syncthreads();
    unsigned* pp = partial + (size_t)blockIdx.x * NBIN;
    for (int b = t; b < NBIN; b += THREADS) pp[b] = hist[b];
}

__global__ void reduceP_kernel(const unsigned* __restrict__ partial,
                               unsigned* __restrict__ deg, int N) {
    int bin = blockIdx.x * THREADS + threadIdx.x;
    if (bin >= N) return;
    int r = bin >> RSH, lbin = bin & (NBIN - 1);
    unsigned s = 0;
#pragma unroll
    for (int j = 0; j < NCHUNK; ++j) s += partial[(size_t)(j * 8 + r) * NBIN + lbin];
    deg[bin] = s;
}

__global__ void scan1_kernel(const unsigned* __restrict__ indeg,
                             unsigned* __restrict__ offsets,
                             unsigned* __restrict__ blockSums, int N) {
    __shared__ unsigned sdata[256];
    int t = threadIdx.x;
    int base = blockIdx.x * SCAN_CHUNK;
    unsigned v[4], s = 0;
#pragma unroll
    for (int i = 0; i < 4; ++i) {
        int idx = base + t * 4 + i;
        v[i] = (idx < N) ? indeg[idx] : 0u;
        s += v[i];
    }
    sdata[t] = s;
    __syncthreads();
    for (int off = 1; off < 256; off <<= 1) {
        unsigned x = (t >= off) ? sdata[t - off] : 0u;
        __syncthreads();
        sdata[t] += x;
        __syncthreads();
    }
    if (t == 255) blockSums[blockIdx.x] = sdata[255];
    unsigned run = sdata[t] - s;
#pragma unroll
    for (int i = 0; i < 4; ++i) {
        int idx = base + t * 4 + i;
        if (idx < N) offsets[idx] = run;
        run += v[i];
    }
}

__global__ void scan2_kernel(unsigned* __restrict__ blockSums, int nb) {
    __shared__ unsigned sdata[1024];
    int t = threadIdx.x;
    unsigned v = (t < nb) ? blockSums[t] : 0u;
    sdata[t] = v;
    __syncthreads();
    for (int off = 1; off < 1024; off <<= 1) {
        unsigned x = (t >= off) ? sdata[t - off] : 0u;
        __syncthreads();
        sdata[t] += x;
        __syncthreads();
    }
    if (t < nb) blockSums[t] = sdata[t] - v;
}

__global__ void scan3_kernel(unsigned* __restrict__ offsets,
                             const unsigned* __restrict__ blockSums, int N) {
    int i = blockIdx.x * blockDim.x + threadIdx.x;
    if (i < N) offsets[i] += blockSums[i / SCAN_CHUNK];
}

// partial[(j,r)][lbin] := global start of chunk j's segment of bin.
__global__ void pboff_kernel(unsigned* __restrict__ partial,
                             const unsigned* __restrict__ offsets, int N) {
    int bin = blockIdx.x * THREADS + threadIdx.x;
    if (bin >= N) return;
    int r = bin >> RSH, lbin = bin & (NBIN - 1);
    unsigned base = offsets[bin];
    for (int j = 0; j < NCHUNK; ++j) {
        size_t idx = (size_t)(j * 8 + r) * NBIN + lbin;
        unsigned c = partial[idx];
        partial[idx] = base;
        base += c;
    }
}

// Block (j,r): LDS cursors from pboff; scatter region edges once. Zero global atomics.
__global__ void bucket2_kernel(const int2* __restrict__ dstpart,
                               const unsigned* __restrict__ rbase,
                               const unsigned* __restrict__ partial,
                               int* __restrict__ sorted_src, int N) {
    __shared__ unsigned cur[NBIN];
    int r = blockIdx.x & 7, j = blockIdx.x >> 3;
    if (r * NBIN >= N) return;
    int t = threadIdx.x;
    const unsigned* pp = partial + (size_t)blockIdx.x * NBIN;
    for (int b = t; b < NBIN; b += THREADS) cur[b] = pp[b];
    __syncthreads();
    unsigned s0 = rbase[r], s1 = rbase[r + 1];
    unsigned chunk = (s1 - s0 + NCHUNK - 1) >> 5;
    unsigned beg = s0 + j * chunk, end = min(s1, beg + chunk);
    for (unsigned i = beg + t; i < end; i += THREADS) {
        int2 e = dstpart[i];
        unsigned pos = atomicAdd(&cur[e.y & (NBIN - 1)], 1u);
        sorted_src[pos] = e.x;
    }
}

__global__ void transform_kernel(const float* __restrict__ feat, const float* __restrict__ weight,
                                 const float* __restrict__ wtype, const int* __restrict__ tinfo,
                                 const unsigned* __restrict__ outdeg,
                                 unsigned short* __restrict__ h16, int N) {
    __shared__ float W[64 * 64];
    int t = threadIdx.x;
    const float4* w4 = (const float4*)weight;
    float4* W4 = (float4*)W;
#pragma unroll
    for (int i = 0; i < 4; ++i) W4[t + i * 256] = w4[t + i * 256];
    __syncthreads();

    int row = blockIdx.x * blockDim.x + t;
    if (row >= N) return;

    float s = rsqrtf(fmaxf((float)outdeg[row], 1.0f)) * wtype[tinfo[row]];

    float acc[64];
#pragma unroll
    for (int j = 0; j < 64; ++j) acc[j] = 0.0f;

    const float4* frow = (const float4*)(feat + (size_t)row * 64);
    for (int k4 = 0; k4 < 16; ++k4) {
        float4 a4 = frow[k4];
#pragma unroll
        for (int kk = 0; kk < 4; ++kk) {
            float a = (kk == 0) ? a4.x : (kk == 1) ? a4.y : (kk == 2) ? a4.z : a4.w;
            const float4* wr = (const float4*)&W[(k4 * 4 + kk) * 64];
#pragma unroll
            for (int j4 = 0; j4 < 16; ++j4) {
                float4 w = wr[j4];  // wave-uniform LDS address -> broadcast
                acc[j4 * 4 + 0] += a * w.x;
                acc[j4 * 4 + 1] += a * w.y;
                acc[j4 * 4 + 2] += a * w.z;
                acc[j4 * 4 + 3] += a * w.w;
            }
        }
    }

    unsigned int* hrow = (unsigned int*)(h16 + (size_t)row * 64);
#pragma unroll
    for (int j2 = 0; j2 < 32; ++j2) {
        unsigned int p = f2bf(acc[2 * j2] * s) | (f2bf(acc[2 * j2 + 1] * s) << 16);
        __builtin_nontemporal_store(p, hrow + j2);
    }
}

// One wave per dst node; lane = (edge parity, feature pair). 2 edges per wave-load.
__global__ void gather_kernel(const int* __restrict__ sorted_src,
                              const unsigned* __restrict__ offsets,
                              const unsigned* __restrict__ indeg,
                              const unsigned short* __restrict__ h16,
                              const float* __restrict__ bias,
                              float* __restrict__ out, int N, int bpt) {
    int team = blockIdx.x & 7;
    int bidx = blockIdx.x >> 3;
    int vblock = team * bpt + bidx;
    int node = vblock * 4 + (threadIdx.x >> 6);
    if (node >= N) return;
    int lane = threadIdx.x & 63;
    int half = lane >> 5;
    int fp = lane & 31;

    unsigned beg = offsets[node];
    unsigned cnt = indeg[node];
    unsigned end = beg + cnt;
    unsigned i = beg;
    float ax = 0.0f, ay = 0.0f;

    for (; i + 8 <= end; i += 8) {
#pragma unroll
        for (int k = 0; k < 4; ++k) {
            unsigned j = i + 2 * k + half;
            int sidx = sorted_src[j];
            unsigned u = *(const unsigned*)(h16 + ((size_t)sidx << 6) + (fp << 1));
            ax += __uint_as_float(u << 16);
            ay += __uint_as_float(u & 0xffff0000u);
        }
    }
    for (; i + 2 <= end; i += 2) {
        unsigned j = i + half;
        int sidx = sorted_src[j];
        unsigned u = *(const unsigned*)(h16 + ((size_t)sidx << 6) + (fp << 1));
        ax += __uint_as_float(u << 16);
        ay += __uint_as_float(u & 0xffff0000u);
    }
    if (i < end) {  // odd tail: only lower half contributes
        int sidx = sorted_src[i];
        unsigned u = *(const unsigned*)(h16 + ((size_t)sidx << 6) + (fp << 1));
        if (half == 0) {
            ax += __uint_as_float(u << 16);
            ay += __uint_as_float(u & 0xffff0000u);
        }
    }

    ax += __shfl_xor(ax, 32, 64);
    ay += __shfl_xor(ay, 32, 64);

    if (half == 0) {
        float sc = rsqrtf(fmaxf((float)cnt, 1.0f));
        float2 b = *(const float2*)(bias + (fp << 1));
        float* op = out + ((size_t)node << 6) + (fp << 1);
        __builtin_nontemporal_store(ax * sc + b.x, op);
        __builtin_nontemporal_store(ay * sc + b.y, op + 1);
    }
}

extern "C" void kernel_launch(void* const* d_in, const int* in_sizes, int n_in,
                              void* d_out, int out_size, void* d_ws, size_t ws_size,
                              hipStream_t stream) {
    const float* feat   = (const float*)d_in[0];
    const float* weight = (const float*)d_in[1];
    const float* wtype  = (const float*)d_in[2];
    const float* bias   = (const float*)d_in[3];
    const int*   src    = (const int*)d_in[4];
    const int*   dst    = (const int*)d_in[5];
    const int*   tinfo  = (const int*)d_in[6];

    int E = in_sizes[4];
    int N = in_sizes[6];
    float* out = (float*)d_out;
    int pchunk = (E + PSLICE - 1) / PSLICE;

    // Workspace: partial 16MB | blobB=max(dstpart, h16) 12.8MB (h16 aliases dstpart;
    //            dstpart dead after bucket2, transform runs later) | srcpart 6.4MB |
    //            sorted_src 6.4MB | counts/bases/rbase | outdeg indeg offsets | blockSums
    size_t partial_bytes = (size_t)NCHUNK * 8 * NBIN * sizeof(unsigned);
    size_t dstpart_bytes = (size_t)E * sizeof(int2);
    size_t h16_bytes = (size_t)N * 64 * sizeof(unsigned short);
    size_t blobB = dstpart_bytes > h16_bytes ? dstpart_bytes : h16_bytes;

    char* ws = (char*)d_ws;
    unsigned* partial   = (unsigned*)ws;                 ws += partial_bytes;
    int2* dstpart       = (int2*)ws;
    unsigned short* h16 = (unsigned short*)dstpart;      ws += blobB;
    int* srcpart        = (int*)ws;                      ws += (size_t)E * sizeof(int);
    int* sorted_src     = (int*)ws;                      ws += (size_t)E * sizeof(int);
    unsigned* countsD   = (unsigned*)ws;                 ws += PSLICE * 8 * sizeof(unsigned);
    unsigned* countsS   = (unsigned*)ws;                 ws += PSLICE * 8 * sizeof(unsigned);
    unsigned* dbase     = (unsigned*)ws;                 ws += PSLICE * 8 * sizeof(unsigned);
    unsigned* sbase     = (unsigned*)ws;                 ws += PSLICE * 8 * sizeof(unsigned);
    unsigned* rbaseD    = (unsigned*)ws;                 ws += 16 * sizeof(unsigned);
    unsigned* rbaseS    = (unsigned*)ws;                 ws += 16 * sizeof(unsigned);
    unsigned* outdeg    = (unsigned*)ws;                 ws += (size_t)N * sizeof(unsigned);
    unsigned* indeg     = (unsigned*)ws;                 ws += (size_t)N * sizeof(unsigned);
    unsigned* offsets   = (unsigned*)ws;                 ws += (size_t)N * sizeof(unsigned);
    unsigned* blockSums = (unsigned*)ws;                 ws += 1024 * sizeof(unsigned);

    countA_kernel<<<PSLICE, THREADS, 0, stream>>>(src, dst, countsD, countsS, E, pchunk);
    scanC_kernel<<<1, 1024, 0, stream>>>(countsD, dbase, rbaseD, E);
    scanC_kernel<<<1, 1024, 0, stream>>>(countsS, sbase, rbaseS, E);
    partition_kernel<<<PSLICE, THREADS, 0, stream>>>(src, dst, dbase, sbase, dstpart, srcpart, E, pchunk);

    histP_kernel<<<NCHUNK * 8, THREADS, 0, stream>>>((const int*)dstpart, 2, 1, rbaseD, partial, N);
    reduceP_kernel<<<(N + THREADS - 1) / THREADS, THREADS, 0, stream>>>(partial, indeg, N);

    int nb = (N + SCAN_CHUNK - 1) / SCAN_CHUNK;
    scan1_kernel<<<nb, 256, 0, stream>>>(indeg, offsets, blockSums, N);
    scan2_kernel<<<1, 1024, 0, stream>>>(blockSums, nb);
    scan3_kernel<<<(N + THREADS - 1) / THREADS, THREADS, 0, stream>>>(offsets, blockSums, N);
    pboff_kernel<<<(N + THREADS - 1) / THREADS, THREADS, 0, stream>>>(partial, offsets, N);

    bucket2_kernel<<<NCHUNK * 8, THREADS, 0, stream>>>(dstpart, rbaseD, partial, sorted_src, N);

    histP_kernel<<<NCHUNK * 8, THREADS, 0, stream>>>(srcpart, 1, 0, rbaseS, partial, N);
    reduceP_kernel<<<(N + THREADS - 1) / THREADS, THREADS, 0, stream>>>(partial, outdeg, N);

    transform_kernel<<<(N + THREADS - 1) / THREADS, THREADS, 0, stream>>>(
        feat, weight, wtype, tinfo, outdeg, h16, N);

    int node_blocks = (N + 3) / 4;
    int bpt = (node_blocks + 7) / 8;
    gather_kernel<<<bpt * 8, THREADS, 0, stream>>>(sorted_src, offsets, indeg, h16, bias, out, N, bpt);
}